// Round 8
// baseline (113.491 us; speedup 1.0000x reference)
//
#include <hip/hip_runtime.h>

// Decoder: N=4096 LSTM seqs (K=16 x B=256), H=64, T=50, GMM head (GC=16, PD=2).
// Round 8: 512 blocks x 512 threads (8 waves) x 8 samples, 2 blocks/CU.
//  - Role-constant weights in LDS (not VGPRs) -> no spill, 4 waves/SIMD:
//      Whh bf16-RNE B-frags 32KB (2-pass gates: h_hi*W + h_lo*W),
//      proj bf16 B-frags 12KB.
//  - Sample s lives on A-row 2s (odd rows zero): every LSTM lane owns exactly
//    2 cell elements (D rows 4g, 4g+2), gc lands in-lane from own prologue GEMM.
//  - waves 0-3 LSTM (4 gate tiles each, units 16w..16w+15), waves 4-5 proj
//    (3 tiles each), waves 6-7 GMM. ONE barrier/step, H/PL double-buffered.

#define T_ 50
typedef __attribute__((ext_vector_type(8))) short short8;
typedef __attribute__((ext_vector_type(4))) float f32x4;
#define MFMA(a,b,c) __builtin_amdgcn_mfma_f32_16x16x32_bf16(a,b,c,0,0,0)

__device__ __forceinline__ float sigf(float x)  { return 1.0f / (1.0f + __expf(-x)); }
__device__ __forceinline__ float tanh_(float x) { return 1.0f - 2.0f / (__expf(2.0f * x) + 1.0f); }

__device__ __forceinline__ void splitf(float f, unsigned short& hi, unsigned short& lo) {
    unsigned b = __float_as_uint(f);
    hi = (unsigned short)(b >> 16);
    float fh = __uint_as_float(b & 0xffff0000u);
    lo = (unsigned short)(__float_as_uint(f - fh) >> 16);
}
__device__ __forceinline__ void pack8(const float* p, short8& hi, short8& lo) {
    #pragma unroll
    for (int e = 0; e < 8; ++e) {
        unsigned short h, l;
        splitf(p[e], h, l);
        hi[e] = (short)h; lo[e] = (short)l;
    }
}
__device__ __forceinline__ unsigned short bf16rn(float f) {
    unsigned b = __float_as_uint(f);
    unsigned r = b + 0x7fffu + ((b >> 16) & 1u);
    return (unsigned short)(r >> 16);
}
__device__ __forceinline__ void pack8rn(const float* p, short8& hi) {
    #pragma unroll
    for (int e = 0; e < 8; ++e) hi[e] = (short)bf16rn(p[e]);
}

__launch_bounds__(512, 4)
__global__ void decoder_kernel(
    const float* __restrict__ x,       const float* __restrict__ z,
    const float* __restrict__ inp_seqs,const float* __restrict__ pred_seqs,
    const float* __restrict__ Wh0,     const float* __restrict__ bh0,
    const float* __restrict__ Wc0,     const float* __restrict__ bc0,
    const float* __restrict__ Wih,     const float* __restrict__ Whh,
    const float* __restrict__ bih,     const float* __restrict__ bhh,
    const float* __restrict__ Wpi,     const float* __restrict__ bpi,
    const float* __restrict__ Wmu,     const float* __restrict__ bmu,
    const float* __restrict__ Wls,     const float* __restrict__ bls,
    const float* __restrict__ Wcorr,   const float* __restrict__ bcorr,
    float* __restrict__ out)
{
    // float layout:
    // [0,8192)      WhhF: 32 B-frag slots (bf16 RNE), slot=(q*4+ub)*2+ks
    // [8192,11264)  PrjF: 12 slots, slot=pt*2+ks
    // [11264,13568) HF: HF0h,HF0l,HF1h,HF1l (each 16x72 ushorts = 576 floats)
    //               C0X overlays HF1 during prologue
    // [13568,18752) ZXL (prologue, 16x324) / {PL0,PL1,FUT,PRS} (loop)
    __shared__ __align__(16) float smem[18752];
    short8* WHH = (short8*)smem;
    short8* PRJ = (short8*)(smem + 8192);
    unsigned short* HF0h = (unsigned short*)(smem + 11264);
    unsigned short* HF0l = (unsigned short*)(smem + 11840);
    unsigned short* HF1h = (unsigned short*)(smem + 12416);
    unsigned short* HF1l = (unsigned short*)(smem + 12992);
    float* C0X = smem + 12416;
    float* ZXL = smem + 13568;
    float* PL0 = smem + 13568;
    float* PL1 = smem + 15168;
    float* FUT = smem + 16768;
    float* PRS = smem + 17568;

    const int j = threadIdx.x;
    const int w = j >> 6;     // wave 0..7
    const int l = j & 63;
    const int g = l >> 4;
    const int c = l & 15;
    const int blk = blockIdx.x;

    // ---- 1) zero ZXL + HF0
    for (int e = j; e < 5184; e += 512) ZXL[e] = 0.0f;
    for (int e = j; e < 1152; e += 512) smem[11264 + e] = 0.0f;
    __syncthreads();

    // ---- 2) fill ZXL even rows; pack Whh/proj frags to LDS (bf16 RNE)
    for (int e = j; e < 8*320; e += 512) {
        int s = e / 320, k = e - s*320;
        int n = blk*8 + s, b = n & 255;
        ZXL[(2*s)*324 + k] = (k < 64) ? z[n*64 + k] : x[b*256 + (k - 64)];
    }
    for (int e = j; e < 2816; e += 512) {
        int lane = e & 63, slot = e >> 6;
        int gg = lane >> 4, cc = lane & 15;
        short8 hi;
        if (slot < 32) {
            int ks = slot & 1, tile = slot >> 1;       // tile = q*4+ub
            int q = tile >> 2, ub = tile & 3;
            pack8rn(Whh + (q*64 + 16*ub + cc)*64 + ks*32 + gg*8, hi);
            WHH[slot*64 + lane] = hi;
        } else {
            int s2 = slot - 32;                        // pt*2+ks
            int ks = s2 & 1, pt = s2 >> 1;
            int r3 = pt*16 + cc;
            const float* p;
            if      (r3 < 16) p = Wpi   + r3*64;
            else if (r3 < 48) p = Wmu   + (r3-16)*64;
            else if (r3 < 80) p = Wls   + (r3-48)*64;
            else              p = Wcorr + (r3-80)*64;
            pack8rn(p + ks*32 + gg*8, hi);
            PRJ[s2*64 + lane] = hi;
        }
    }
    __syncthreads();

    // ---- 3) prologue GEMMs (3-pass, full precision, from global W)
    float gc0v[4], gc1v[4], wd0[4], wd1[4];
    float cst0 = 0.0f, cst1 = 0.0f;
    float biasP[3] = {0.0f, 0.0f, 0.0f};
    float sum = 0.0f;
    const int s3 = 4*(w - 6) + g;   // GMM sample (w>=6)

    if (w < 4) {
        f32x4 gcA[4];
        #pragma unroll
        for (int q = 0; q < 4; ++q) {
            int ga = q*64 + 16*w + c;
            float b_ = bih[ga] + bhh[ga];
            gcA[q] = (f32x4){b_, 0.0f, b_, 0.0f};
            wd0[q] = Wih[ga*322 + 320];
            wd1[q] = Wih[ga*322 + 321];
        }
        for (int ks = 0; ks < 10; ++ks) {
            short8 ah, al;
            pack8(&ZXL[c*324 + ks*32 + g*8], ah, al);
            #pragma unroll
            for (int q = 0; q < 4; ++q) {
                int ga = q*64 + 16*w + c;
                short8 bh_, bl_;
                pack8(Wih + ga*322 + ks*32 + g*8, bh_, bl_);
                gcA[q] = MFMA(ah, bh_, gcA[q]);
                gcA[q] = MFMA(ah, bl_, gcA[q]);
                gcA[q] = MFMA(al, bh_, gcA[q]);
            }
        }
        #pragma unroll
        for (int q = 0; q < 4; ++q) { gc0v[q] = gcA[q][0]; gc1v[q] = gcA[q][2]; }
    } else {
        int v = w - 4, u = 16*v + c;
        float bhv = bh0[u], bcv = bc0[u];
        f32x4 h0a = (f32x4){bhv, 0.0f, bhv, 0.0f};
        f32x4 c0a = (f32x4){bcv, 0.0f, bcv, 0.0f};
        for (int ks = 0; ks < 10; ++ks) {
            short8 ah, al, bh_, bl_, ch_, cl_;
            pack8(&ZXL[c*324 + ks*32 + g*8], ah, al);
            pack8(Wh0 + u*320 + ks*32 + g*8, bh_, bl_);
            pack8(Wc0 + u*320 + ks*32 + g*8, ch_, cl_);
            h0a = MFMA(ah, bh_, h0a); h0a = MFMA(ah, bl_, h0a); h0a = MFMA(al, bh_, h0a);
            c0a = MFMA(ah, ch_, c0a); c0a = MFMA(ah, cl_, c0a); c0a = MFMA(al, ch_, c0a);
        }
        unsigned short hh, ll;
        splitf(h0a[0], hh, ll); HF0h[(4*g)*72 + u] = hh;   HF0l[(4*g)*72 + u] = ll;
        splitf(h0a[2], hh, ll); HF0h[(4*g+2)*72 + u] = hh; HF0l[(4*g+2)*72 + u] = ll;
        C0X[(2*g)*64 + u]   = c0a[0];
        C0X[(2*g+1)*64 + u] = c0a[2];
    }
    __syncthreads();

    // ---- 4) role pickup
    if (w < 4) {
        cst0 = C0X[(2*g)*64 + 16*w + c];
        cst1 = C0X[(2*g+1)*64 + 16*w + c];
    } else if (w < 6) {
        #pragma unroll
        for (int i = 0; i < 3; ++i) {
            int r3 = (3*(w-4) + i)*16 + c;
            biasP[i] = (r3 < 16) ? bpi[r3] : (r3 < 48) ? bmu[r3-16]
                     : (r3 < 80) ? bls[r3-48] : bcorr[r3-80];
        }
    }
    __syncthreads();

    // ---- 5) zero HF1 (was C0X); stage FUT/PRS (ZXL dead)
    for (int e = j; e < 1152; e += 512) smem[12416 + e] = 0.0f;
    for (int e = j; e < T_*16; e += 512) {
        int t = e >> 4, rem = e & 15, s = rem >> 1;
        int b = (blk*8 + s) & 255;
        FUT[e] = pred_seqs[b*1200 + t*24 + 20 + (rem & 1)];
    }
    if (j < 16) {
        int b = (blk*8 + (j >> 1)) & 255;
        PRS[j] = inp_seqs[b*192 + 188 + (j & 1)];
    }
    __syncthreads();

    auto do_gmm = [&](const float* pl, const float* fut2) {
        const float* pls = pl + (2*s3)*100;
        float a_pi = pls[c];
        float a_m0 = pls[16 + 2*c], a_m1 = pls[17 + 2*c];
        float l0   = pls[48 + 2*c], l1   = pls[49 + 2*c];
        float a_co = pls[80 + c];
        float v0 = fut2[s3*2], v1 = fut2[s3*2 + 1];
        l0 = fminf(fmaxf(l0, -10.0f), 10.0f);
        l1 = fminf(fmaxf(l1, -10.0f), 10.0f);
        float z0 = (v0 - a_m0) * __expf(-l0);
        float z1 = (v1 - a_m1) * __expf(-l1);
        float ct = tanh_(a_co);
        float omr = 1.0f - ct*ct;
        float quad = z0*z0 + z1*z1 - 2.0f*ct*z0*z1;
        float comp = -1.8378770664093453f - (l0 + l1) - 0.5f*__logf(omr) - 0.5f*quad/omr;
        float a = a_pi + comp;
        float m1v = a, m2v = a_pi;
        #pragma unroll
        for (int off = 1; off < 16; off <<= 1) {
            m1v = fmaxf(m1v, __shfl_xor(m1v, off));
            m2v = fmaxf(m2v, __shfl_xor(m2v, off));
        }
        float e1 = __expf(a - m1v), e2 = __expf(a_pi - m2v);
        #pragma unroll
        for (int off = 1; off < 16; off <<= 1) {
            e1 += __shfl_xor(e1, off);
            e2 += __shfl_xor(e2, off);
        }
        float logp = (m1v + __logf(e1)) - (m2v + __logf(e2));
        sum += fminf(logp, 50.0f);
    };
    auto do_proj = [&](const unsigned short* Hh, const unsigned short* Hl, float* PLw) {
        short8 ah0 = *reinterpret_cast<const short8*>(Hh + c*72 +      g*8);
        short8 al0 = *reinterpret_cast<const short8*>(Hl + c*72 +      g*8);
        short8 ah1 = *reinterpret_cast<const short8*>(Hh + c*72 + 32 + g*8);
        short8 al1 = *reinterpret_cast<const short8*>(Hl + c*72 + 32 + g*8);
        #pragma unroll
        for (int i = 0; i < 3; ++i) {
            int pt = 3*(w-4) + i;
            short8 B0 = PRJ[(pt*2 + 0)*64 + l];
            short8 B1 = PRJ[(pt*2 + 1)*64 + l];
            f32x4 p = (f32x4){biasP[i], biasP[i], biasP[i], biasP[i]};
            p = MFMA(ah0, B0, p); p = MFMA(al0, B0, p);
            p = MFMA(ah1, B1, p); p = MFMA(al1, B1, p);
            PLw[(4*g)*100 + pt*16 + c]   = p[0];
            PLw[(4*g+2)*100 + pt*16 + c] = p[2];
        }
    };

    // ---- 6) main loop: ONE barrier per step
    for (int t = 0; t < T_; ++t) {
        const unsigned short* Hh = (t & 1) ? HF1h : HF0h;
        const unsigned short* Hl = (t & 1) ? HF1l : HF0l;
        if (w < 4) {
            unsigned short* Nh = (t & 1) ? HF0h : HF1h;
            unsigned short* Nl = (t & 1) ? HF0l : HF1l;
            short8 ah0 = *reinterpret_cast<const short8*>(Hh + c*72 +      g*8);
            short8 al0 = *reinterpret_cast<const short8*>(Hl + c*72 +      g*8);
            short8 ah1 = *reinterpret_cast<const short8*>(Hh + c*72 + 32 + g*8);
            short8 al1 = *reinterpret_cast<const short8*>(Hl + c*72 + 32 + g*8);
            const float* dptr = (t == 0) ? PRS : (FUT + (t-1)*16);
            float2 d0 = *reinterpret_cast<const float2*>(dptr + 4*g);
            float2 d1 = *reinterpret_cast<const float2*>(dptr + 4*g + 2);
            __builtin_amdgcn_s_setprio(1);
            f32x4 aq[4];
            #pragma unroll
            for (int q = 0; q < 4; ++q) {
                f32x4 a;
                a[0] = gc0v[q] + d0.x*wd0[q] + d0.y*wd1[q];
                a[1] = 0.0f;
                a[2] = gc1v[q] + d1.x*wd0[q] + d1.y*wd1[q];
                a[3] = 0.0f;
                short8 B0 = WHH[((q*4 + w)*2 + 0)*64 + l];
                short8 B1 = WHH[((q*4 + w)*2 + 1)*64 + l];
                a = MFMA(ah0, B0, a);
                a = MFMA(al0, B0, a);
                a = MFMA(ah1, B1, a);
                a = MFMA(al1, B1, a);
                aq[q] = a;
            }
            float cc0 = sigf(aq[1][0])*cst0 + sigf(aq[0][0])*tanh_(aq[2][0]);
            float cc1 = sigf(aq[1][2])*cst1 + sigf(aq[0][2])*tanh_(aq[2][2]);
            cst0 = cc0; cst1 = cc1;
            float hv0 = sigf(aq[3][0])*tanh_(cc0);
            float hv1 = sigf(aq[3][2])*tanh_(cc1);
            __builtin_amdgcn_s_setprio(0);
            unsigned short hh, ll;
            splitf(hv0, hh, ll);
            Nh[(4*g)*72 + 16*w + c] = hh;   Nl[(4*g)*72 + 16*w + c] = ll;
            splitf(hv1, hh, ll);
            Nh[(4*g+2)*72 + 16*w + c] = hh; Nl[(4*g+2)*72 + 16*w + c] = ll;
        } else if (w < 6) {
            if (t >= 1) do_proj(Hh, Hl, (t & 1) ? PL1 : PL0);
        } else {
            if (t >= 2) do_gmm((t & 1) ? PL0 : PL1, FUT + (t-2)*16);
        }
        __syncthreads();
    }

    // ---- 7) epilogue: proj(H_50)->PL0; GMM(H_49)=PL1; sync; GMM(H_50)=PL0
    if (w == 4 || w == 5) do_proj(HF0h, HF0l, PL0);
    if (w >= 6) do_gmm(PL1, FUT + 48*16);
    __syncthreads();
    if (w >= 6) {
        do_gmm(PL0, FUT + 49*16);
        if (c == 0) out[blk*8 + s3] = sum;
    }
}

extern "C" void kernel_launch(void* const* d_in, const int* in_sizes, int n_in,
                              void* d_out, int out_size, void* d_ws, size_t ws_size,
                              hipStream_t stream) {
    const float* x     = (const float*)d_in[0];
    const float* z     = (const float*)d_in[1];
    const float* iseq  = (const float*)d_in[2];
    const float* pseq  = (const float*)d_in[3];
    const float* Wh0   = (const float*)d_in[4];
    const float* bh0   = (const float*)d_in[5];
    const float* Wc0   = (const float*)d_in[6];
    const float* bc0   = (const float*)d_in[7];
    const float* Wih   = (const float*)d_in[8];
    const float* Whh   = (const float*)d_in[9];
    const float* bih   = (const float*)d_in[10];
    const float* bhh   = (const float*)d_in[11];
    const float* Wpi   = (const float*)d_in[12];
    const float* bpi   = (const float*)d_in[13];
    const float* Wmu   = (const float*)d_in[14];
    const float* bmu   = (const float*)d_in[15];
    const float* Wls   = (const float*)d_in[16];
    const float* bls   = (const float*)d_in[17];
    const float* Wcorr = (const float*)d_in[18];
    const float* bcorr = (const float*)d_in[19];
    float* out = (float*)d_out;

    decoder_kernel<<<512, 512, 0, stream>>>(x, z, iseq, pseq, Wh0, bh0, Wc0, bc0,
                                            Wih, Whh, bih, bhh, Wpi, bpi, Wmu, bmu,
                                            Wls, bls, Wcorr, bcorr, out);
}

// Round 9
// 110.733 us; speedup vs baseline: 1.0249x; 1.0249x over previous
//
#include <hip/hip_runtime.h>

// Decoder: N=4096 LSTM seqs (K=16 x B=256), H=64, T=50, GMM head (GC=16, PD=2).
// Round 9: minimal-loop split.
//  k0: pack weights into MFMA B-frag layout in ws (Wih/Wh0/Wc0 hi/lo, Whh RNE,
//      proj hi/lo).
//  k1: recurrence ONLY. 256 blocks x 4 waves x 16 samples (full tiles).
//      Wave w owns gate tiles i/f/g/o for units [16w,16w+16); gc/c0 land
//      in-lane from the wave's own prologue tiles; Whh bf16-RNE in VGPRs
//      (2-pass h_hi/h_lo => 16 MFMA/step); raw s_barrier + lgkmcnt-only wait
//      (h->global store never drains vmcnt in-loop).
//  k2: proj + GMM, fully parallel (1024 blocks), MFMA proj + in-lane GMM,
//      atomicAdd into zeroed d_out (R5-proven).

#define T_ 50
typedef __attribute__((ext_vector_type(8))) short short8;
typedef __attribute__((ext_vector_type(4))) float f32x4;
#define MFMA(a,b,c) __builtin_amdgcn_mfma_f32_16x16x32_bf16(a,b,c,0,0,0)

// ws layout (bytes): Hout ushort[50][4096][64] = 26,214,400 ; WF short8[34304]
#define HOUT_B 0u
#define WF_B   26214400u
// WF slot bases (short8-slot units; addr = (BASE+rel)*64 + lane)
#define WIH_S 0
#define WH0_S 320
#define WC0_S 400
#define WHH_S 480
#define PRJ_S 512

__device__ __forceinline__ float sigf(float x)  { return 1.0f / (1.0f + __expf(-x)); }
__device__ __forceinline__ float tanh_(float x) { return 1.0f - 2.0f / (__expf(2.0f * x) + 1.0f); }

__device__ __forceinline__ void splitf(float f, unsigned short& hi, unsigned short& lo) {
    unsigned b = __float_as_uint(f);
    hi = (unsigned short)(b >> 16);
    float fh = __uint_as_float(b & 0xffff0000u);
    lo = (unsigned short)(__float_as_uint(f - fh) >> 16);
}
__device__ __forceinline__ void pack8(const float* p, short8& hi, short8& lo) {
    #pragma unroll
    for (int e = 0; e < 8; ++e) {
        unsigned short h, l;
        splitf(p[e], h, l);
        hi[e] = (short)h; lo[e] = (short)l;
    }
}
__device__ __forceinline__ unsigned short bf16rn(float f) {
    unsigned b = __float_as_uint(f);
    unsigned r = b + 0x7fffu + ((b >> 16) & 1u);
    return (unsigned short)(r >> 16);
}
__device__ __forceinline__ void pack8rn(const float* p, short8& hi) {
    #pragma unroll
    for (int e = 0; e < 8; ++e) hi[e] = (short)bf16rn(p[e]);
}

// ---------------- k0: weight packing ----------------
__global__ void pack_kernel(const float* __restrict__ Wih, const float* __restrict__ Whh,
                            const float* __restrict__ Wh0, const float* __restrict__ Wc0,
                            const float* __restrict__ Wpi, const float* __restrict__ Wmu,
                            const float* __restrict__ Wls, const float* __restrict__ Wcorr,
                            short8* __restrict__ WF)
{
    int id = blockIdx.x * 256 + threadIdx.x;
    if (id >= 18176) return;
    if (id < 10240) {                               // Wih hi/lo
        int ks = id >> 10, rem = id & 1023;
        int q = rem >> 8, w = (rem >> 6) & 3, l = rem & 63;
        int g = l >> 4, c = l & 15;
        const float* src = Wih + (q*64 + w*16 + c)*322 + ks*32 + g*8;
        short8 hi, lo; pack8(src, hi, lo);
        WF[(WIH_S + ((ks*4 + q)*2 + 0)*4 + w)*64 + l] = hi;
        WF[(WIH_S + ((ks*4 + q)*2 + 1)*4 + w)*64 + l] = lo;
    } else if (id < 12800) {                        // Wh0 hi/lo
        int t2 = id - 10240;
        int ks = t2 >> 8, w = (t2 >> 6) & 3, l = t2 & 63;
        int g = l >> 4, c = l & 15;
        const float* src = Wh0 + (w*16 + c)*320 + ks*32 + g*8;
        short8 hi, lo; pack8(src, hi, lo);
        WF[(WH0_S + (ks*2 + 0)*4 + w)*64 + l] = hi;
        WF[(WH0_S + (ks*2 + 1)*4 + w)*64 + l] = lo;
    } else if (id < 15360) {                        // Wc0 hi/lo
        int t2 = id - 12800;
        int ks = t2 >> 8, w = (t2 >> 6) & 3, l = t2 & 63;
        int g = l >> 4, c = l & 15;
        const float* src = Wc0 + (w*16 + c)*320 + ks*32 + g*8;
        short8 hi, lo; pack8(src, hi, lo);
        WF[(WC0_S + (ks*2 + 0)*4 + w)*64 + l] = hi;
        WF[(WC0_S + (ks*2 + 1)*4 + w)*64 + l] = lo;
    } else if (id < 17408) {                        // Whh RNE single-plane
        int t3 = id - 15360;
        int slot = t3 >> 6, l = t3 & 63;
        int g = l >> 4, c = l & 15;
        int tile = slot >> 1, ks = slot & 1;
        int q = tile >> 2, wt = tile & 3;
        short8 hi; pack8rn(Whh + (q*64 + 16*wt + c)*64 + ks*32 + g*8, hi);
        WF[(WHH_S + slot)*64 + l] = hi;
    } else {                                        // proj hi/lo
        int t4 = id - 17408;
        int r = t4 >> 6, l = t4 & 63;
        int g = l >> 4, c = l & 15;
        int pt = r >> 1, ks = r & 1;
        int r3 = pt*16 + c;
        const float* p;
        if      (r3 < 16) p = Wpi   + r3*64;
        else if (r3 < 48) p = Wmu   + (r3-16)*64;
        else if (r3 < 80) p = Wls   + (r3-48)*64;
        else              p = Wcorr + (r3-80)*64;
        short8 hi, lo; pack8(p + ks*32 + g*8, hi, lo);
        WF[(PRJ_S + ((pt*2 + ks)*2 + 0))*64 + l] = hi;
        WF[(PRJ_S + ((pt*2 + ks)*2 + 1))*64 + l] = lo;
    }
}

// ---------------- k1: LSTM recurrence only ----------------
__launch_bounds__(256, 2)
__global__ void lstm_kernel(
    const float* __restrict__ x,        const float* __restrict__ z,
    const float* __restrict__ inp_seqs, const float* __restrict__ pred_seqs,
    const float* __restrict__ Wih,      const float* __restrict__ bh0,
    const float* __restrict__ bc0,      const float* __restrict__ bih,
    const float* __restrict__ bhh,
    unsigned short* __restrict__ Hout,  const short8* __restrict__ WF)
{
    // floats: ZXL [0,5184) 16x324 (prologue) / DQ [0,1600) 50x16x2 (loop)
    //         HF planes: 5184 h0hi, 5472 h0lo, 5760 h1hi, 6048 h1lo (16x72 ushort)
    __shared__ __align__(16) float smem[6336];
    float* ZXL = smem;
    float* DQ  = smem;
    unsigned short* HF0h = (unsigned short*)(smem + 5184);
    unsigned short* HF0l = (unsigned short*)(smem + 5472);
    unsigned short* HF1h = (unsigned short*)(smem + 5760);
    unsigned short* HF1l = (unsigned short*)(smem + 6048);

    const int j = threadIdx.x;
    const int w = j >> 6, l = j & 63, g = l >> 4, c = l & 15;
    const int U = 16*w + c;
    const int blk = blockIdx.x, nb = blk*16;

    // ---- stage zx
    for (int e = j; e < 16*320; e += 256) {
        int s = e / 320, k = e - s*320;
        int n = nb + s, b = n & 255;
        ZXL[s*324 + k] = (k < 64) ? z[n*64 + k] : x[b*256 + (k - 64)];
    }
    __syncthreads();

    // ---- prologue GEMM: wave w computes gc tiles {q*4+w}, h0 tile w, c0 tile w
    f32x4 gcA[4], h0a, c0a;
    {
        #pragma unroll
        for (int q = 0; q < 4; ++q) {
            int ga = q*64 + U;
            float b_ = bih[ga] + bhh[ga];
            gcA[q] = (f32x4){b_, b_, b_, b_};
        }
        float bh_ = bh0[U], bc_ = bc0[U];
        h0a = (f32x4){bh_, bh_, bh_, bh_};
        c0a = (f32x4){bc_, bc_, bc_, bc_};
    }
    for (int ks = 0; ks < 10; ++ks) {
        short8 ah, al;
        pack8(&ZXL[c*324 + ks*32 + g*8], ah, al);
        #pragma unroll
        for (int q = 0; q < 4; ++q) {
            short8 Bh = WF[(WIH_S + ((ks*4 + q)*2 + 0)*4 + w)*64 + l];
            short8 Bl = WF[(WIH_S + ((ks*4 + q)*2 + 1)*4 + w)*64 + l];
            gcA[q] = MFMA(ah, Bh, gcA[q]);
            gcA[q] = MFMA(ah, Bl, gcA[q]);
            gcA[q] = MFMA(al, Bh, gcA[q]);
        }
        {
            short8 Bh = WF[(WH0_S + (ks*2 + 0)*4 + w)*64 + l];
            short8 Bl = WF[(WH0_S + (ks*2 + 1)*4 + w)*64 + l];
            h0a = MFMA(ah, Bh, h0a); h0a = MFMA(ah, Bl, h0a); h0a = MFMA(al, Bh, h0a);
        }
        {
            short8 Bh = WF[(WC0_S + (ks*2 + 0)*4 + w)*64 + l];
            short8 Bl = WF[(WC0_S + (ks*2 + 1)*4 + w)*64 + l];
            c0a = MFMA(ah, Bh, c0a); c0a = MFMA(ah, Bl, c0a); c0a = MFMA(al, Bh, c0a);
        }
    }
    // h0 -> HF0 (hi/lo); c0 in-lane
    float cst[4];
    #pragma unroll
    for (int r = 0; r < 4; ++r) {
        cst[r] = c0a[r];
        unsigned short hh, ll; splitf(h0a[r], hh, ll);
        HF0h[(4*g + r)*72 + U] = hh;
        HF0l[(4*g + r)*72 + U] = ll;
    }
    // d-weights + Whh RNE frags
    float wd0[4], wd1[4];
    #pragma unroll
    for (int q = 0; q < 4; ++q) {
        int ga = q*64 + U;
        wd0[q] = Wih[ga*322 + 320];
        wd1[q] = Wih[ga*322 + 321];
    }
    short8 WB[4][2];
    #pragma unroll
    for (int q = 0; q < 4; ++q)
        #pragma unroll
        for (int ks = 0; ks < 2; ++ks)
            WB[q][ks] = WF[(WHH_S + (q*4 + w)*2 + ks)*64 + l];
    __syncthreads();   // ZXL dead

    // ---- stage DQ (t=0 present, t>=1 FUT[t-1])
    for (int e = j; e < T_*32; e += 256) {
        int t = e >> 5, rem = e & 31, s = rem >> 1, comp = rem & 1;
        int b = (nb + s) & 255;
        DQ[e] = (t == 0) ? inp_seqs[b*192 + 188 + comp]
                         : pred_seqs[b*1200 + (t-1)*24 + 20 + comp];
    }
    __syncthreads();

    // ---- main loop: raw barrier (lgkmcnt-only), vmcnt never drained
    for (int t = 0; t < T_; ++t) {
        const unsigned short* Hh = (t & 1) ? HF1h : HF0h;
        const unsigned short* Hl = (t & 1) ? HF1l : HF0l;
        unsigned short* Nh = (t & 1) ? HF0h : HF1h;
        unsigned short* Nl = (t & 1) ? HF0l : HF1l;

        short8 ah0 = *reinterpret_cast<const short8*>(Hh + c*72 +      g*8);
        short8 al0 = *reinterpret_cast<const short8*>(Hl + c*72 +      g*8);
        short8 ah1 = *reinterpret_cast<const short8*>(Hh + c*72 + 32 + g*8);
        short8 al1 = *reinterpret_cast<const short8*>(Hl + c*72 + 32 + g*8);
        f32x4 dA = *reinterpret_cast<const f32x4*>(DQ + t*32 + 8*g);
        f32x4 dB = *reinterpret_cast<const f32x4*>(DQ + t*32 + 8*g + 4);

        f32x4 aq[4];
        #pragma unroll
        for (int q = 0; q < 4; ++q) {
            f32x4 a;
            a[0] = gcA[q][0] + dA[0]*wd0[q] + dA[1]*wd1[q];
            a[1] = gcA[q][1] + dA[2]*wd0[q] + dA[3]*wd1[q];
            a[2] = gcA[q][2] + dB[0]*wd0[q] + dB[1]*wd1[q];
            a[3] = gcA[q][3] + dB[2]*wd0[q] + dB[3]*wd1[q];
            a = MFMA(ah0, WB[q][0], a);
            a = MFMA(al0, WB[q][0], a);
            a = MFMA(ah1, WB[q][1], a);
            a = MFMA(al1, WB[q][1], a);
            aq[q] = a;
        }
        #pragma unroll
        for (int r = 0; r < 4; ++r) {
            float cc = sigf(aq[1][r])*cst[r] + sigf(aq[0][r])*tanh_(aq[2][r]);
            cst[r] = cc;
            float hv = sigf(aq[3][r])*tanh_(cc);
            unsigned short hh, ll; splitf(hv, hh, ll);
            Nh[(4*g + r)*72 + U] = hh;
            Nl[(4*g + r)*72 + U] = ll;
            Hout[(size_t)(t*4096 + nb + 4*g + r)*64 + U] = hh;
        }
        asm volatile("s_waitcnt lgkmcnt(0)" ::: "memory");
        __builtin_amdgcn_s_barrier();
        asm volatile("" ::: "memory");
    }
}

// ---------------- k2: proj + GMM ----------------
__launch_bounds__(256, 3)
__global__ void head_kernel(const float* __restrict__ pred_seqs,
                            const float* __restrict__ bpi, const float* __restrict__ bmu,
                            const float* __restrict__ bls, const float* __restrict__ bcorr,
                            const unsigned short* __restrict__ Hin,
                            const short8* __restrict__ WF,
                            float* __restrict__ out)
{
    __shared__ __align__(16) float PL[4][1600];   // per-wave 16 x 100
    const int j = threadIdx.x;
    const int w = j >> 6;
    const int l = j & 63;
    const int g = l >> 4;
    const int c = l & 15;
    const int blk = blockIdx.x;
    const int set = blk >> 2, chunk = blk & 3;
    const int t0 = (chunk*25) >> 1, t1 = ((chunk+1)*25) >> 1;

    float bias[6];
    #pragma unroll
    for (int pt = 0; pt < 6; ++pt) {
        int r3 = pt*16 + c;
        bias[pt] = (r3 < 16) ? bpi[r3] : (r3 < 48) ? bmu[r3-16]
                 : (r3 < 80) ? bls[r3-48] : bcorr[r3-80];
    }

    const int s = l >> 2, q4 = l & 3;
    const int n_s = set*16 + s, b_s = n_s & 255;
    float* PLw = &PL[w][0];
    float sum_local = 0.0f;

    for (int t = t0 + w; t < t1; t += 4) {
        const unsigned short* hp = Hin + (size_t)(t*4096 + set*16 + c)*64;
        short8 ah0 = *reinterpret_cast<const short8*>(hp + g*8);
        short8 ah1 = *reinterpret_cast<const short8*>(hp + 32 + g*8);
        #pragma unroll
        for (int pt = 0; pt < 6; ++pt) {
            short8 B00 = WF[(PRJ_S + ((pt*2 + 0)*2 + 0))*64 + l];
            short8 B01 = WF[(PRJ_S + ((pt*2 + 0)*2 + 1))*64 + l];
            short8 B10 = WF[(PRJ_S + ((pt*2 + 1)*2 + 0))*64 + l];
            short8 B11 = WF[(PRJ_S + ((pt*2 + 1)*2 + 1))*64 + l];
            f32x4 p = (f32x4){bias[pt], bias[pt], bias[pt], bias[pt]};
            p = MFMA(ah0, B00, p);
            p = MFMA(ah0, B01, p);
            p = MFMA(ah1, B10, p);
            p = MFMA(ah1, B11, p);
            #pragma unroll
            for (int r = 0; r < 4; ++r) PLw[(4*g + r)*100 + pt*16 + c] = p[r];
        }
        asm volatile("s_waitcnt lgkmcnt(0)" ::: "memory");
        __builtin_amdgcn_sched_barrier(0);

        float2 tv = *reinterpret_cast<const float2*>(pred_seqs + b_s*1200 + t*24 + 20);
        float a[4], m = -1e30f, Ppi = 0.0f;
        #pragma unroll
        for (int i = 0; i < 4; ++i) {
            int cq = q4*4 + i;
            float pi = PLw[s*100 + cq];
            float2 mu = *reinterpret_cast<const float2*>(PLw + s*100 + 16 + 2*cq);
            float2 ls = *reinterpret_cast<const float2*>(PLw + s*100 + 48 + 2*cq);
            float co = PLw[s*100 + 80 + cq];
            float l0 = fminf(fmaxf(ls.x, -10.0f), 10.0f);
            float l1 = fminf(fmaxf(ls.y, -10.0f), 10.0f);
            float z0 = (tv.x - mu.x) * __expf(-l0);
            float z1 = (tv.y - mu.y) * __expf(-l1);
            float ct = tanh_(co);
            float omr = 1.0f - ct*ct;
            float quad = z0*z0 + z1*z1 - 2.0f*ct*z0*z1;
            float comp = -1.8378770664093453f - (l0 + l1) - 0.5f*__logf(omr) - 0.5f*quad/omr;
            a[i] = pi + comp;
            m = fmaxf(m, a[i]);
            Ppi += __expf(pi);
        }
        m = fmaxf(m, __shfl_xor(m, 1));
        m = fmaxf(m, __shfl_xor(m, 2));
        float E = __expf(a[0]-m) + __expf(a[1]-m) + __expf(a[2]-m) + __expf(a[3]-m);
        E   += __shfl_xor(E, 1);   E   += __shfl_xor(E, 2);
        Ppi += __shfl_xor(Ppi, 1); Ppi += __shfl_xor(Ppi, 2);
        float logp = m + __logf(E) - __logf(Ppi);
        sum_local += fminf(logp, 50.0f);
    }
    if (q4 == 0) atomicAdd(out + n_s, sum_local);
}

extern "C" void kernel_launch(void* const* d_in, const int* in_sizes, int n_in,
                              void* d_out, int out_size, void* d_ws, size_t ws_size,
                              hipStream_t stream) {
    const float* x     = (const float*)d_in[0];
    const float* z     = (const float*)d_in[1];
    const float* iseq  = (const float*)d_in[2];
    const float* pseq  = (const float*)d_in[3];
    const float* Wh0   = (const float*)d_in[4];
    const float* bh0   = (const float*)d_in[5];
    const float* Wc0   = (const float*)d_in[6];
    const float* bc0   = (const float*)d_in[7];
    const float* Wih   = (const float*)d_in[8];
    const float* Whh   = (const float*)d_in[9];
    const float* bih   = (const float*)d_in[10];
    const float* bhh   = (const float*)d_in[11];
    const float* Wpi   = (const float*)d_in[12];
    const float* bpi   = (const float*)d_in[13];
    const float* Wmu   = (const float*)d_in[14];
    const float* bmu   = (const float*)d_in[15];
    const float* Wls   = (const float*)d_in[16];
    const float* bls   = (const float*)d_in[17];
    const float* Wcorr = (const float*)d_in[18];
    const float* bcorr = (const float*)d_in[19];
    float* out = (float*)d_out;

    char* ws = (char*)d_ws;
    unsigned short* Hout = (unsigned short*)(ws + HOUT_B);
    short8* WF = (short8*)(ws + WF_B);

    pack_kernel<<<71, 256, 0, stream>>>(Wih, Whh, Wh0, Wc0, Wpi, Wmu, Wls, Wcorr, WF);
    hipMemsetAsync(d_out, 0, 4096 * sizeof(float), stream);
    lstm_kernel<<<256, 256, 0, stream>>>(x, z, iseq, pseq, Wih, bh0, bc0, bih, bhh,
                                         Hout, (const short8*)WF);
    head_kernel<<<1024, 256, 0, stream>>>(pseq, bpi, bmu, bls, bcorr,
                                          (const unsigned short*)Hout,
                                          (const short8*)WF, out);
}